// Round 2
// baseline (956.652 us; speedup 1.0000x reference)
//
#include <hip/hip_runtime.h>
#include <cstdint>
#include <cstddef>

typedef _Float16 h16;
typedef _Float16 h16x8 __attribute__((ext_vector_type(8)));
typedef float f32x4 __attribute__((ext_vector_type(4)));

typedef const uint32_t GU32 __attribute__((address_space(1)));
typedef uint32_t LU32 __attribute__((address_space(3)));

__device__ __forceinline__ void gload_lds16(const void* g, void* l) {
  __builtin_amdgcn_global_load_lds((GU32*)g, (LU32*)l, 16, 0, 0);
}

__device__ __forceinline__ float sigm(float x) { return 1.f / (1.f + __expf(-x)); }

static inline long ceil128(long x) { return (x + 127) & ~127L; }

// ---------------------------------------------------------------------------
// GEMM: C(M,N) = A(M,K) @ Bt(N,K)^T, fp16 in, fp32 accumulate (MFMA 16x16x32).
// m97 structure: 128x128 tile, BK=32, 4 waves, global_load_lds width 16.
// EPI: 0 = raw f32 (split-K partial, C offset by blockIdx.z*M*N)
//      1 = +bias, ReLU, fp16 out
//      2 = +bias, fp16 out
// DUAL: blockIdx.y==1 selects second problem (same M,N,K).
// ---------------------------------------------------------------------------
template <int EPI, bool DUAL>
__global__ __launch_bounds__(256) void gemm_bt(
    const h16* __restrict__ A, const h16* __restrict__ Bt, void* Cv,
    const float* __restrict__ bias, const h16* A2, const h16* Bt2, void* Cv2,
    const float* bias2, int M, int N, int K, int nktSplit) {
  if (DUAL && blockIdx.y == 1) { A = A2; Bt = Bt2; Cv = Cv2; bias = bias2; }
  __shared__ __align__(16) h16 As[4096];
  __shared__ __align__(16) h16 Bs[4096];
  const int tid = threadIdx.x;
  const int lane = tid & 63;
  const int w = tid >> 6;
  const int ntn = N >> 7;
  const int bm = blockIdx.x / ntn;
  const int bn = blockIdx.x - bm * ntn;
  const long m0 = (long)bm << 7;
  const long n0 = (long)bn << 7;
  const int wm = w >> 1, wn = w & 1;

  f32x4 acc[4][4] = {};

  // staging: lane -> row w*16 + lane/4 (+64 for 2nd issue), k-off (lane&3)*8
  const int srow = (w << 4) + (lane >> 2);
  const int skoff = (lane & 3) << 3;
  const h16* Ag = A + (m0 + srow) * K + skoff;
  const h16* Bg = Bt + (n0 + srow) * K + skoff;
  h16* AsW = &As[w << 9];
  h16* BsW = &Bs[w << 9];
  const int lr = lane & 15;
  const int kg = lane >> 4;
  const h16* Ard = &As[((wm << 6) + lr) * 32 + (kg << 3)];
  const h16* Brd = &Bs[((wn << 6) + lr) * 32 + (kg << 3)];

  const int kt0 = blockIdx.z * nktSplit;
  for (int kt = kt0; kt < kt0 + nktSplit; ++kt) {
    const h16* a = Ag + (long)kt * 32;
    const h16* b = Bg + (long)kt * 32;
    gload_lds16(a, AsW);
    gload_lds16(a + (long)64 * K, AsW + 2048);
    gload_lds16(b, BsW);
    gload_lds16(b + (long)64 * K, BsW + 2048);
    __syncthreads();  // drains vmcnt: LDS tile ready
    h16x8 af[4], bfr[4];
#pragma unroll
    for (int f = 0; f < 4; ++f) {
      af[f] = *(const h16x8*)(Ard + (f << 9));
      bfr[f] = *(const h16x8*)(Brd + (f << 9));
    }
#pragma unroll
    for (int fm = 0; fm < 4; ++fm)
#pragma unroll
      for (int fn = 0; fn < 4; ++fn)
        acc[fm][fn] = __builtin_amdgcn_mfma_f32_16x16x32_f16(af[fm], bfr[fn],
                                                             acc[fm][fn], 0, 0, 0);
    __syncthreads();  // all reads done before next overwrite
  }

  float* Cf = (float*)Cv;
  if (EPI == 0) Cf += (long)blockIdx.z * M * N;
  h16* Ch = (h16*)Cv;
#pragma unroll
  for (int fm = 0; fm < 4; ++fm)
#pragma unroll
    for (int fn = 0; fn < 4; ++fn)
#pragma unroll
      for (int j = 0; j < 4; ++j) {
        long row = m0 + (wm << 6) + (fm << 4) + (kg << 2) + j;
        long col = n0 + (wn << 6) + (fn << 4) + lr;
        float v = acc[fm][fn][j];
        if (EPI == 0) {
          Cf[row * N + col] = v;
        } else {
          v += bias[col];
          if (EPI == 1) v = fmaxf(v, 0.f);
          Ch[row * N + col] = (h16)v;
        }
      }
}

// ---------------------------------------------------------------------------
// im2col for conv1: x (G,128,7,7) f32 -> P (G*36, 512) fp16.
// row r = g*36 + py*6 + px ; col k = ch*4 + ky*2 + kx. Thread = (r, k-pair).
// ---------------------------------------------------------------------------
__global__ void im2col1_kernel(const float* __restrict__ x, h16* __restrict__ P) {
  long idx = (long)blockIdx.x * 256 + threadIdx.x;  // grid sized exactly CG*36 blocks
  int kp = (int)(idx & 255);
  long r = idx >> 8;
  int g = (int)(r / 36);
  int p = (int)(r - (long)g * 36);
  int py = p / 6, px = p - py * 6;
  int ch = kp >> 1;
  int ky = kp & 1;
  const float* src = x + ((long)g * 128 + ch) * 49 + (py + ky) * 7 + px;
  h16* dst = P + r * 512 + kp * 2;
  dst[0] = (h16)src[0];
  dst[1] = (h16)src[1];
}

// ---------------------------------------------------------------------------
// pool1 + im2col for conv2: C1 (CG*36, 1024) fp16 (relu'd) -> P2 (CG*4, 4096).
// ---------------------------------------------------------------------------
__global__ void pool1_kernel(const h16* __restrict__ C1, h16* __restrict__ P2) {
  long idx = (long)blockIdx.x * 256 + threadIdx.x;  // grid: CG*64
  int k2 = (int)(idx & 4095);
  long r2 = idx >> 12;
  int g = (int)(r2 >> 2);
  int p2 = (int)(r2 & 3);
  int ch = k2 >> 2;
  int ky = (k2 >> 1) & 1, kx = k2 & 1;
  int yp = (p2 >> 1) + ky, xp = (p2 & 1) + kx;
  const h16* base = C1 + (long)g * 36 * 1024 + ch;
  float m = 0.f;  // relu'd inputs are >= 0
#pragma unroll
  for (int dy = 0; dy < 2; ++dy)
#pragma unroll
    for (int dx = 0; dx < 2; ++dx) {
      float v = (float)base[((2 * yp + dy) * 6 + (2 * xp + dx)) * 1024];
      m = fmaxf(m, v);
    }
  P2[idx] = (h16)m;
}

// ---------------------------------------------------------------------------
// pool2 + bias + relu over split-K partial sums -> feat rows (fp16).
// ---------------------------------------------------------------------------
__global__ void pool2_kernel(const float* __restrict__ C2, long partStride,
                             int nparts, const float* __restrict__ bias,
                             h16* __restrict__ featb, int Gvalid) {
  long idx = (long)blockIdx.x * 256 + threadIdx.x;  // grid: CG*2
  int o = (int)(idx & 511);
  long m = idx >> 9;
  if (m >= Gvalid) return;
  float s0 = 0, s1 = 0, s2 = 0, s3 = 0;
  for (int s = 0; s < nparts; ++s) {
    const float* bp = C2 + (long)s * partStride + m * 2048 + o;
    s0 += bp[0]; s1 += bp[512]; s2 += bp[1024]; s3 += bp[1536];
  }
  float v = fmaxf(fmaxf(s0, s1), fmaxf(s2, s3)) + bias[o];
  featb[idx] = (h16)fmaxf(v, 0.f);
}

// GRU with h=0: gh reduces to b_hh broadcast. Gates stored fp16.
__global__ void gru_init_kernel(const h16* __restrict__ gi,
                                const float* __restrict__ b_hh,
                                float* __restrict__ h, h16* __restrict__ hb) {
  long idx = (long)blockIdx.x * 256 + threadIdx.x;
  int j = (int)(idx & 511);
  long m = idx >> 9;
  const h16* g = gi + m * 1536;
  float r = sigm((float)g[j] + b_hh[j]);
  float z = sigm((float)g[512 + j] + b_hh[512 + j]);
  float n = tanhf((float)g[1024 + j] + r * b_hh[1024 + j]);
  float hv = (1.f - z) * n;
  h[idx] = hv;
  hb[idx] = (h16)hv;
}

__global__ void gru_step_kernel(const h16* __restrict__ gi,
                                const h16* __restrict__ gh,
                                float* __restrict__ h, h16* __restrict__ hb) {
  long idx = (long)blockIdx.x * 256 + threadIdx.x;
  int j = (int)(idx & 511);
  long m = idx >> 9;
  const h16* a = gi + m * 1536;
  const h16* b = gh + m * 1536;
  float r = sigm((float)a[j] + (float)b[j]);
  float z = sigm((float)a[512 + j] + (float)b[512 + j]);
  float n = tanhf((float)a[1024 + j] + r * (float)b[1024 + j]);
  float hv = (1.f - z) * n + z * h[idx];
  h[idx] = hv;
  hb[idx] = (h16)hv;
}

// ---------------------------------------------------------------------------
// Message kernel: one wave per edge row (re = b*992 + e).
// ---------------------------------------------------------------------------
__global__ void message_kernel(const float* __restrict__ h_n,
                               const float* __restrict__ h_e,
                               const int* __restrict__ eidx,
                               const float* __restrict__ wnp,
                               const float* __restrict__ wps,
                               const float* __restrict__ wpo,
                               h16* __restrict__ msg_eb,
                               h16* __restrict__ nm_e, int istride) {
  int re = blockIdx.x * 4 + (threadIdx.x >> 6);
  int lane = threadIdx.x & 63;
  int b = re / 992;
  int e = re - b * 992;
  long base = ((long)b * 992 + e) * 3;
  int s = eidx[(base + 1) * istride];
  int o = eidx[(base + 2) * istride];
  const float* ns = h_n + (long)(b * 32 + s) * 512;
  const float* no = h_n + (long)(b * 32 + o) * 512;
  const float* eh = h_e + (long)re * 512;
  float dn = 0, ds = 0, dob = 0;
  for (int t = lane; t < 512; t += 64) {
    float nsv = ns[t], nov = no[t], ehv = eh[t];
    dn += nsv * wnp[t] + ehv * wnp[512 + t];
    ds += nsv * wps[t] + ehv * wps[512 + t];
    dob += nov * wpo[t] + ehv * wpo[512 + t];
  }
#pragma unroll
  for (int off = 32; off; off >>= 1) {
    dn += __shfl_xor(dn, off);
    ds += __shfl_xor(ds, off);
    dob += __shfl_xor(dob, off);
  }
  float sn = sigm(dn), ss = sigm(ds), so = sigm(dob);
  for (int t = lane; t < 512; t += 64) {
    msg_eb[(long)re * 512 + t] = (h16)(ss * ns[t] + so * no[t]);
    nm_e[(long)re * 512 + t] = (h16)(sn * eh[t]);
  }
}

// Deterministic node-message gather: block per (b,n), scan all edges.
__global__ void gather_kernel(const h16* __restrict__ nm_e,
                              const int* __restrict__ eidx,
                              h16* __restrict__ msg_nb, int istride) {
  int b = blockIdx.x >> 5;
  int n = blockIdx.x & 31;
  int t = threadIdx.x;
  float a0 = 0, a1 = 0;
  const int* eb = eidx + (long)b * 992 * 3 * istride;
  for (int e = 0; e < 992; ++e) {
    int s = eb[(e * 3 + 1) * istride], o = eb[(e * 3 + 2) * istride];
    if (s == n || o == n) {
      const h16* src = nm_e + ((long)b * 992 + e) * 512;
      a0 += (float)src[t];
      a1 += (float)src[t + 256];
    }
  }
  h16* d = msg_nb + (long)(b * 32 + n) * 512;
  d[t] = (h16)a0;
  d[t + 256] = (h16)a1;
}

// Fused f32->fp16 conversion of all 8 weight matrices.
struct Cvt8 {
  const float* s[8];
  h16* d[8];
  long cum[9];
};
__global__ void cvt8_kernel(Cvt8 j) {
  long idx = (long)blockIdx.x * 256 + threadIdx.x;
  if (idx >= j.cum[8]) return;
  int seg = 0;
  while (idx >= j.cum[seg + 1]) ++seg;
  long off = idx - j.cum[seg];
  j.d[seg][off] = (h16)j.s[seg][off];
}

__global__ void out_kernel(const float* __restrict__ h_n,
                           const float* __restrict__ h_e,
                           float* __restrict__ out) {
  long i = (long)blockIdx.x * 256 + threadIdx.x;  // 1048576 total
  out[i] = (i < 32768) ? h_n[i] : h_e[i - 32768];
}

// ws-too-small diagnostic: zero output, out[0] encodes ws_size in MB.
__global__ void diag_kernel(float* out, int n, float v) {
  int i = blockIdx.x * 256 + threadIdx.x;
  if (i < n) out[i] = (i == 0) ? v : 0.f;
}

// ---------------------------------------------------------------------------
extern "C" void kernel_launch(void* const* d_in, const int* in_sizes, int n_in,
                              void* d_out, int out_size, void* d_ws,
                              size_t ws_size, hipStream_t stream) {
  const float* node_lat = (const float*)d_in[0];
  const float* edge_lat = (const float*)d_in[1];
  const int* eidx = (const int*)d_in[2];
  const float* ncw1 = (const float*)d_in[3];
  const float* ncb1 = (const float*)d_in[4];
  const float* ncw2 = (const float*)d_in[5];
  const float* ncb2 = (const float*)d_in[6];
  const float* ecw1 = (const float*)d_in[7];
  const float* ecb1 = (const float*)d_in[8];
  const float* ecw2 = (const float*)d_in[9];
  const float* ecb2 = (const float*)d_in[10];
  const float* nwih = (const float*)d_in[11];
  const float* nwhh = (const float*)d_in[12];
  const float* nbih = (const float*)d_in[13];
  const float* nbhh = (const float*)d_in[14];
  const float* ewih = (const float*)d_in[15];
  const float* ewhh = (const float*)d_in[16];
  const float* ebih = (const float*)d_in[17];
  const float* ebhh = (const float*)d_in[18];
  const float* wnp = (const float*)d_in[19];
  const float* wps = (const float*)d_in[20];
  const float* wpo = (const float*)d_in[21];

  const int istride = (in_sizes[2] == 2 * 992 * 3 * 2) ? 2 : 1;

  char* wsb = (char*)d_ws;
  size_t cur = 0;
  auto alloc = [&](size_t b) -> char* {
    char* p = wsb + cur;
    cur += (b + 255) & ~(size_t)255;
    return p;
  };

  // ---- fixed region (~43.4 MB) ----
  h16* W1rn = (h16*)alloc(1024 * 512 * 2);
  h16* W1re = (h16*)alloc(1024 * 512 * 2);
  h16* W2rn = (h16*)alloc((size_t)512 * 4096 * 2);
  h16* W2re = (h16*)alloc((size_t)512 * 4096 * 2);
  h16* Wihn = (h16*)alloc(1536 * 512 * 2);
  h16* Whhn = (h16*)alloc(1536 * 512 * 2);
  h16* Wihe = (h16*)alloc(1536 * 512 * 2);
  h16* Whhe = (h16*)alloc(1536 * 512 * 2);
  h16* featbn = (h16*)alloc(128 * 512 * 2);
  h16* featbe = (h16*)alloc(2048 * 512 * 2);
  float* h_n = (float*)alloc(128 * 512 * 4);
  h16* h_nb = (h16*)alloc(128 * 512 * 2);
  float* h_e = (float*)alloc(2048 * 512 * 4);
  h16* h_eb = (h16*)alloc(2048 * 512 * 2);
  h16* gi_n = (h16*)alloc(128 * 1536 * 2);
  h16* gh_n = (h16*)alloc(128 * 1536 * 2);
  h16* gi_e = (h16*)alloc((size_t)2048 * 1536 * 2);
  h16* gh_e = (h16*)alloc((size_t)2048 * 1536 * 2);
  h16* msg_nb = (h16*)alloc(128 * 512 * 2);
  h16* msg_eb = (h16*)alloc(2048 * 512 * 2);
  h16* nm_e = (h16*)alloc(2048 * 512 * 2);

  // ---- adaptive chunk scratch ----
  const long tiers[3] = {248, 124, 62};
  long CG = 0, M1cap = 0, P2R = 0;
  for (int t = 0; t < 3; ++t) {
    long cg = tiers[t];
    long m1r = cg * 36; if (m1r < 2304) m1r = 2304;
    long m1 = ceil128(m1r);
    long p2r = cg * 4; if (p2r < 256) p2r = 256;
    p2r = ceil128(p2r);
    size_t chunkB = (size_t)m1 * 512 * 2 + (size_t)m1 * 1024 * 2 +
                    (size_t)p2r * 4096 * 2 + (size_t)p2r * 512 * 4 * 8 + 1024;
    if (cur + chunkB <= ws_size) { CG = cg; M1cap = m1; P2R = p2r; break; }
  }
  if (!CG) {  // diagnostic: zero output, out[0] = ws MB
    diag_kernel<<<(out_size + 255) / 256, 256, 0, stream>>>(
        (float*)d_out, out_size, (float)((double)ws_size * 1e-6));
    return;
  }
  h16* P1 = (h16*)alloc((size_t)M1cap * 512 * 2);
  h16* C1 = (h16*)alloc((size_t)M1cap * 1024 * 2);
  h16* P2 = (h16*)alloc((size_t)P2R * 4096 * 2);
  float* C2 = (float*)alloc((size_t)P2R * 512 * 4 * 8);  // 8 split-K parts

  // ---- weight conversion (one fused launch) ----
  Cvt8 cj;
  const float* srcs[8] = {ncw1, ecw1, ncw2, ecw2, nwih, nwhh, ewih, ewhh};
  h16* dsts[8] = {W1rn, W1re, W2rn, W2re, Wihn, Whhn, Wihe, Whhe};
  long sizes[8] = {1024 * 512, 1024 * 512, (long)512 * 4096, (long)512 * 4096,
                   1536 * 512, 1536 * 512, 1536 * 512, 1536 * 512};
  long c = 0;
  for (int i = 0; i < 8; ++i) {
    cj.s[i] = srcs[i];
    cj.d[i] = dsts[i];
    cj.cum[i] = c;
    c += sizes[i];
  }
  cj.cum[8] = c;
  cvt8_kernel<<<(unsigned)((c + 255) / 256), 256, 0, stream>>>(cj);

  // ---- CNN encoder (chunked) ----
  auto encoder = [&](const float* x, const h16* W1, const float* b1,
                     const h16* W2, const float* b2, h16* featb, long G,
                     long cg) {
    for (long g0 = 0; g0 < G; g0 += cg) {
      long m1 = ceil128(cg * 36);
      long m2 = ceil128(cg * 4);
      im2col1_kernel<<<(unsigned)(cg * 36), 256, 0, stream>>>(
          x + g0 * 128 * 49, P1);
      gemm_bt<1, false><<<(unsigned)((m1 >> 7) * 8), 256, 0, stream>>>(
          P1, W1, C1, b1, nullptr, nullptr, nullptr, nullptr, (int)m1, 1024,
          512, 16);
      pool1_kernel<<<(unsigned)(cg * 64), 256, 0, stream>>>(C1, P2);
      gemm_bt<0, false><<<dim3((unsigned)(m2 >> 5), 1, 8), 256, 0, stream>>>(
          P2, W2, C2, nullptr, nullptr, nullptr, nullptr, nullptr, (int)m2,
          512, 4096, 16);
      pool2_kernel<<<(unsigned)(cg * 2), 256, 0, stream>>>(
          C2, m2 * 512L, 8, b2, featb + g0 * 512, (int)cg);
    }
  };
  encoder(node_lat, W1rn, ncb1, W2rn, ncb2, featbn, 64, 64);
  encoder(edge_lat, W1re, ecb1, W2re, ecb2, featbe, 1984, CG);

  // ---- initial GRU (h = 0) ----
  gemm_bt<2, false><<<12, 256, 0, stream>>>(
      featbn, Wihn, gi_n, nbih, nullptr, nullptr, nullptr, nullptr, 128, 1536,
      512, 16);
  gru_init_kernel<<<128, 256, 0, stream>>>(gi_n, nbhh, h_n, h_nb);
  gemm_bt<2, false><<<16 * 12, 256, 0, stream>>>(
      featbe, Wihe, gi_e, ebih, nullptr, nullptr, nullptr, nullptr, 2048, 1536,
      512, 16);
  gru_init_kernel<<<3968, 256, 0, stream>>>(gi_e, ebhh, h_e, h_eb);

  // ---- 2 message-passing iterations (ref's 3rd iteration output is dead) ----
  for (int it = 0; it < 2; ++it) {
    message_kernel<<<496, 256, 0, stream>>>(h_n, h_e, eidx, wnp, wps, wpo,
                                            msg_eb, nm_e, istride);
    gather_kernel<<<64, 256, 0, stream>>>(nm_e, eidx, msg_nb, istride);
    gemm_bt<2, true><<<dim3(12, 2), 256, 0, stream>>>(
        msg_nb, Wihn, gi_n, nbih, h_nb, Whhn, gh_n, nbhh, 128, 1536, 512, 16);
    gemm_bt<2, true><<<dim3(16 * 12, 2), 256, 0, stream>>>(
        msg_eb, Wihe, gi_e, ebih, h_eb, Whhe, gh_e, ebhh, 2048, 1536, 512, 16);
    gru_step_kernel<<<128, 256, 0, stream>>>(gi_n, gh_n, h_n, h_nb);
    gru_step_kernel<<<3968, 256, 0, stream>>>(gi_e, gh_e, h_e, h_eb);
  }

  // ---- output: nh (64x512) then eh (1984x512), both f32 ----
  out_kernel<<<4096, 256, 0, stream>>>(h_n, h_e, (float*)d_out);
}

// Round 3
// 634.566 us; speedup vs baseline: 1.5076x; 1.5076x over previous
//
#include <hip/hip_runtime.h>
#include <cstdint>
#include <cstddef>

typedef _Float16 h16;
typedef _Float16 h16x2 __attribute__((ext_vector_type(2)));
typedef _Float16 h16x8 __attribute__((ext_vector_type(8)));
typedef float f32x4 __attribute__((ext_vector_type(4)));

typedef const uint32_t GU32 __attribute__((address_space(1)));
typedef uint32_t LU32 __attribute__((address_space(3)));

__device__ __forceinline__ void gload_lds16(const void* g, void* l) {
  __builtin_amdgcn_global_load_lds((GU32*)g, (LU32*)l, 16, 0, 0);
}

__device__ __forceinline__ float sigm(float x) { return 1.f / (1.f + __expf(-x)); }

static inline long ceil128(long x) { return (x + 127) & ~127L; }

// ---------------------------------------------------------------------------
// GEMM: C(M,N) = A(M,K) @ Bt(N,K)^T, fp16 in, fp32 accumulate (MFMA 16x16x32).
// m97 structure: 128x128 tile, BK=32, 4 waves, global_load_lds width 16.
// EPI: 0 = raw f32 (split-K partial, C offset by blockIdx.z*M*N)
//      1 = +bias, ReLU, fp16 out
//      2 = +bias, fp16 out
// DUAL: blockIdx.y==1 selects second problem (same M,N,K).
// ---------------------------------------------------------------------------
template <int EPI, bool DUAL>
__global__ __launch_bounds__(256) void gemm_bt(
    const h16* __restrict__ A, const h16* __restrict__ Bt, void* Cv,
    const float* __restrict__ bias, const h16* A2, const h16* Bt2, void* Cv2,
    const float* bias2, int M, int N, int K, int nktSplit) {
  if (DUAL && blockIdx.y == 1) { A = A2; Bt = Bt2; Cv = Cv2; bias = bias2; }
  __shared__ __align__(16) h16 As[4096];
  __shared__ __align__(16) h16 Bs[4096];
  const int tid = threadIdx.x;
  const int lane = tid & 63;
  const int w = tid >> 6;
  const int ntn = N >> 7;
  const int bm = blockIdx.x / ntn;
  const int bn = blockIdx.x - bm * ntn;
  const long m0 = (long)bm << 7;
  const long n0 = (long)bn << 7;
  const int wm = w >> 1, wn = w & 1;

  f32x4 acc[4][4] = {};

  const int srow = (w << 4) + (lane >> 2);
  const int skoff = (lane & 3) << 3;
  const h16* Ag = A + (m0 + srow) * K + skoff;
  const h16* Bg = Bt + (n0 + srow) * K + skoff;
  h16* AsW = &As[w << 9];
  h16* BsW = &Bs[w << 9];
  const int lr = lane & 15;
  const int kg = lane >> 4;
  const h16* Ard = &As[((wm << 6) + lr) * 32 + (kg << 3)];
  const h16* Brd = &Bs[((wn << 6) + lr) * 32 + (kg << 3)];

  const int kt0 = blockIdx.z * nktSplit;
  for (int kt = kt0; kt < kt0 + nktSplit; ++kt) {
    const h16* a = Ag + (long)kt * 32;
    const h16* b = Bg + (long)kt * 32;
    gload_lds16(a, AsW);
    gload_lds16(a + (long)64 * K, AsW + 2048);
    gload_lds16(b, BsW);
    gload_lds16(b + (long)64 * K, BsW + 2048);
    __syncthreads();
    h16x8 af[4], bfr[4];
#pragma unroll
    for (int f = 0; f < 4; ++f) {
      af[f] = *(const h16x8*)(Ard + (f << 9));
      bfr[f] = *(const h16x8*)(Brd + (f << 9));
    }
#pragma unroll
    for (int fm = 0; fm < 4; ++fm)
#pragma unroll
      for (int fn = 0; fn < 4; ++fn)
        acc[fm][fn] = __builtin_amdgcn_mfma_f32_16x16x32_f16(af[fm], bfr[fn],
                                                             acc[fm][fn], 0, 0, 0);
    __syncthreads();
  }

  float* Cf = (float*)Cv;
  if (EPI == 0) Cf += (long)blockIdx.z * M * N;
  h16* Ch = (h16*)Cv;
#pragma unroll
  for (int fm = 0; fm < 4; ++fm)
#pragma unroll
    for (int fn = 0; fn < 4; ++fn)
#pragma unroll
      for (int j = 0; j < 4; ++j) {
        long row = m0 + (wm << 6) + (fm << 4) + (kg << 2) + j;
        long col = n0 + (wn << 6) + (fn << 4) + lr;
        float v = acc[fm][fn][j];
        if (EPI == 0) {
          Cf[row * N + col] = v;
        } else {
          v += bias[col];
          if (EPI == 1) v = fmaxf(v, 0.f);
          Ch[row * N + col] = (h16)v;
        }
      }
}

// im2col for conv1: x (G,128,7,7) f32 -> P (G*36, 512) fp16.
__global__ void im2col1_kernel(const float* __restrict__ x, h16* __restrict__ P) {
  long idx = (long)blockIdx.x * 256 + threadIdx.x;
  int kp = (int)(idx & 255);
  long r = idx >> 8;
  int g = (int)(r / 36);
  int p = (int)(r - (long)g * 36);
  int py = p / 6, px = p - py * 6;
  int ch = kp >> 1;
  int ky = kp & 1;
  const float* src = x + ((long)g * 128 + ch) * 49 + (py + ky) * 7 + px;
  h16* dst = P + r * 512 + kp * 2;
  dst[0] = (h16)src[0];
  dst[1] = (h16)src[1];
}

// pool1 + im2col for conv2: C1 (CG*36, 1024) fp16 (relu'd) -> P2 (CG*4, 4096).
__global__ void pool1_kernel(const h16* __restrict__ C1, h16* __restrict__ P2) {
  long idx = (long)blockIdx.x * 256 + threadIdx.x;
  int k2 = (int)(idx & 4095);
  long r2 = idx >> 12;
  int g = (int)(r2 >> 2);
  int p2 = (int)(r2 & 3);
  int ch = k2 >> 2;
  int ky = (k2 >> 1) & 1, kx = k2 & 1;
  int yp = (p2 >> 1) + ky, xp = (p2 & 1) + kx;
  const h16* base = C1 + (long)g * 36 * 1024 + ch;
  float m = 0.f;  // relu'd inputs are >= 0
#pragma unroll
  for (int dy = 0; dy < 2; ++dy)
#pragma unroll
    for (int dx = 0; dx < 2; ++dx) {
      float v = (float)base[((2 * yp + dy) * 6 + (2 * xp + dx)) * 1024];
      m = fmaxf(m, v);
    }
  P2[idx] = (h16)m;
}

// pool2 + bias + relu over split-K partial sums -> feat rows (fp16).
__global__ void pool2_kernel(const float* __restrict__ C2, long partStride,
                             int nparts, const float* __restrict__ bias,
                             h16* __restrict__ featb, int Gvalid) {
  long idx = (long)blockIdx.x * 256 + threadIdx.x;
  int o = (int)(idx & 511);
  long m = idx >> 9;
  if (m >= Gvalid) return;
  float s0 = 0, s1 = 0, s2 = 0, s3 = 0;
  for (int s = 0; s < nparts; ++s) {
    const float* bp = C2 + (long)s * partStride + m * 2048 + o;
    s0 += bp[0]; s1 += bp[512]; s2 += bp[1024]; s3 += bp[1536];
  }
  float v = fmaxf(fmaxf(s0, s1), fmaxf(s2, s3)) + bias[o];
  featb[idx] = (h16)fmaxf(v, 0.f);
}

// GRU with h=0: gh reduces to b_hh broadcast. Gates stored fp16.
__global__ void gru_init_kernel(const h16* __restrict__ gi,
                                const float* __restrict__ b_hh,
                                float* __restrict__ h, h16* __restrict__ hb) {
  long idx = (long)blockIdx.x * 256 + threadIdx.x;
  int j = (int)(idx & 511);
  long m = idx >> 9;
  const h16* g = gi + m * 1536;
  float r = sigm((float)g[j] + b_hh[j]);
  float z = sigm((float)g[512 + j] + b_hh[512 + j]);
  float n = tanhf((float)g[1024 + j] + r * b_hh[1024 + j]);
  float hv = (1.f - z) * n;
  h[idx] = hv;
  hb[idx] = (h16)hv;
}

__global__ void gru_step_kernel(const h16* __restrict__ gi,
                                const h16* __restrict__ gh,
                                float* __restrict__ h, h16* __restrict__ hb) {
  long idx = (long)blockIdx.x * 256 + threadIdx.x;
  int j = (int)(idx & 511);
  long m = idx >> 9;
  const h16* a = gi + m * 1536;
  const h16* b = gh + m * 1536;
  float r = sigm((float)a[j] + (float)b[j]);
  float z = sigm((float)a[512 + j] + (float)b[512 + j]);
  float n = tanhf((float)a[1024 + j] + r * (float)b[1024 + j]);
  float hv = (1.f - z) * n + z * h[idx];
  h[idx] = hv;
  hb[idx] = (h16)hv;
}

// Message kernel: one wave per edge row (re = b*992 + e).
__global__ void message_kernel(const float* __restrict__ h_n,
                               const float* __restrict__ h_e,
                               const int* __restrict__ eidx,
                               const float* __restrict__ wnp,
                               const float* __restrict__ wps,
                               const float* __restrict__ wpo,
                               h16* __restrict__ msg_eb,
                               h16* __restrict__ nm_e, int istride) {
  int re = blockIdx.x * 4 + (threadIdx.x >> 6);
  int lane = threadIdx.x & 63;
  int b = re / 992;
  int e = re - b * 992;
  long base = ((long)b * 992 + e) * 3;
  int s = eidx[(base + 1) * istride];
  int o = eidx[(base + 2) * istride];
  const float* ns = h_n + (long)(b * 32 + s) * 512;
  const float* no = h_n + (long)(b * 32 + o) * 512;
  const float* eh = h_e + (long)re * 512;
  float dn = 0, ds = 0, dob = 0;
  for (int t = lane; t < 512; t += 64) {
    float nsv = ns[t], nov = no[t], ehv = eh[t];
    dn += nsv * wnp[t] + ehv * wnp[512 + t];
    ds += nsv * wps[t] + ehv * wps[512 + t];
    dob += nov * wpo[t] + ehv * wpo[512 + t];
  }
#pragma unroll
  for (int off = 32; off; off >>= 1) {
    dn += __shfl_xor(dn, off);
    ds += __shfl_xor(ds, off);
    dob += __shfl_xor(dob, off);
  }
  float sn = sigm(dn), ss = sigm(ds), so = sigm(dob);
  for (int t = lane; t < 512; t += 64) {
    msg_eb[(long)re * 512 + t] = (h16)(ss * ns[t] + so * no[t]);
    nm_e[(long)re * 512 + t] = (h16)(sn * eh[t]);
  }
}

// ---------------------------------------------------------------------------
// Incidence build: per (b,n), ordered list of 31 subj-edges then 31 obj-edges.
// One wave per (b,n); ballot + prefix-popcount gives deterministic positions.
// ---------------------------------------------------------------------------
__global__ void incid_kernel(const int* __restrict__ eidx,
                             int* __restrict__ elist, int istride) {
  int w = (blockIdx.x << 2) + (threadIdx.x >> 6);  // 16 blocks * 4 waves = 64
  int lane = threadIdx.x & 63;
  int b = w >> 5, n = w & 31;
  const int* eb = eidx + (long)b * 992 * 3 * istride;
  int* dst = elist + w * 62;
  int bs = 0, bo = 0;
  for (int c = 0; c < 16; ++c) {
    int e = c * 64 + lane;
    bool v = e < 992;
    int s = v ? eb[(e * 3 + 1) * istride] : -1;
    int o = v ? eb[(e * 3 + 2) * istride] : -1;
    unsigned long long ms = __ballot(s == n);
    unsigned long long mo = __ballot(o == n);
    unsigned long long below = (1ull << lane) - 1ull;
    if (s == n) {
      int p = bs + __popcll(ms & below);
      if (p < 31) dst[p] = e;
    }
    if (o == n) {
      int p = bo + __popcll(mo & below);
      if (p < 31) dst[31 + p] = e;
    }
    bs += __popcll(ms);
    bo += __popcll(mo);
  }
  // robustness: pad unused slots (shouldn't happen for this input family)
  for (int i = bs + lane; i < 31; i += 64) dst[i] = -1;
  for (int i = bo + lane; i < 31; i += 64) dst[31 + i] = -1;
}

// Node-message gather via incidence lists: block per (b,n), 62 edge rows.
__global__ void gather_kernel(const h16* __restrict__ nm_e,
                              const int* __restrict__ elist,
                              h16* __restrict__ msg_nb) {
  int bn = blockIdx.x;  // 64
  int t = threadIdx.x;  // 256
  int b = bn >> 5;
  const int* lst = elist + bn * 62;
  float a0 = 0.f, a1 = 0.f;
#pragma unroll 2
  for (int i = 0; i < 62; ++i) {
    int e = lst[i];
    if (e < 0) continue;
    h16x2 v = *(const h16x2*)(nm_e + ((long)b * 992 + e) * 512 + t * 2);
    a0 += (float)v.x;
    a1 += (float)v.y;
  }
  h16* d = msg_nb + (long)bn * 512 + t * 2;
  d[0] = (h16)a0;
  d[1] = (h16)a1;
}

// Fused f32->fp16 conversion of all 8 weight matrices.
struct Cvt8 {
  const float* s[8];
  h16* d[8];
  long cum[9];
};
__global__ void cvt8_kernel(Cvt8 j) {
  long idx = (long)blockIdx.x * 256 + threadIdx.x;
  if (idx >= j.cum[8]) return;
  int seg = 0;
  while (idx >= j.cum[seg + 1]) ++seg;
  long off = idx - j.cum[seg];
  j.d[seg][off] = (h16)j.s[seg][off];
}

__global__ void out_kernel(const float* __restrict__ h_n,
                           const float* __restrict__ h_e,
                           float* __restrict__ out) {
  long i = (long)blockIdx.x * 256 + threadIdx.x;  // 1048576 total
  out[i] = (i < 32768) ? h_n[i] : h_e[i - 32768];
}

// ws-too-small diagnostic: zero output, out[0] encodes ws_size in MB.
__global__ void diag_kernel(float* out, int n, float v) {
  int i = blockIdx.x * 256 + threadIdx.x;
  if (i < n) out[i] = (i == 0) ? v : 0.f;
}

// ---------------------------------------------------------------------------
extern "C" void kernel_launch(void* const* d_in, const int* in_sizes, int n_in,
                              void* d_out, int out_size, void* d_ws,
                              size_t ws_size, hipStream_t stream) {
  const float* node_lat = (const float*)d_in[0];
  const float* edge_lat = (const float*)d_in[1];
  const int* eidx = (const int*)d_in[2];
  const float* ncw1 = (const float*)d_in[3];
  const float* ncb1 = (const float*)d_in[4];
  const float* ncw2 = (const float*)d_in[5];
  const float* ncb2 = (const float*)d_in[6];
  const float* ecw1 = (const float*)d_in[7];
  const float* ecb1 = (const float*)d_in[8];
  const float* ecw2 = (const float*)d_in[9];
  const float* ecb2 = (const float*)d_in[10];
  const float* nwih = (const float*)d_in[11];
  const float* nwhh = (const float*)d_in[12];
  const float* nbih = (const float*)d_in[13];
  const float* nbhh = (const float*)d_in[14];
  const float* ewih = (const float*)d_in[15];
  const float* ewhh = (const float*)d_in[16];
  const float* ebih = (const float*)d_in[17];
  const float* ebhh = (const float*)d_in[18];
  const float* wnp = (const float*)d_in[19];
  const float* wps = (const float*)d_in[20];
  const float* wpo = (const float*)d_in[21];

  const int istride = (in_sizes[2] == 2 * 992 * 3 * 2) ? 2 : 1;

  char* wsb = (char*)d_ws;
  size_t cur = 0;
  auto alloc = [&](size_t b) -> char* {
    char* p = wsb + cur;
    cur += (b + 255) & ~(size_t)255;
    return p;
  };

  // ---- fixed region (~43.5 MB) ----
  h16* W1rn = (h16*)alloc(1024 * 512 * 2);
  h16* W1re = (h16*)alloc(1024 * 512 * 2);
  h16* W2rn = (h16*)alloc((size_t)512 * 4096 * 2);
  h16* W2re = (h16*)alloc((size_t)512 * 4096 * 2);
  h16* Wihn = (h16*)alloc(1536 * 512 * 2);
  h16* Whhn = (h16*)alloc(1536 * 512 * 2);
  h16* Wihe = (h16*)alloc(1536 * 512 * 2);
  h16* Whhe = (h16*)alloc(1536 * 512 * 2);
  h16* featbn = (h16*)alloc(128 * 512 * 2);
  h16* featbe = (h16*)alloc(2048 * 512 * 2);
  float* h_n = (float*)alloc(128 * 512 * 4);
  h16* h_nb = (h16*)alloc(128 * 512 * 2);
  float* h_e = (float*)alloc(2048 * 512 * 4);
  h16* h_eb = (h16*)alloc(2048 * 512 * 2);
  h16* gi_n = (h16*)alloc(128 * 1536 * 2);
  h16* gh_n = (h16*)alloc(128 * 1536 * 2);
  h16* gi_e = (h16*)alloc((size_t)2048 * 1536 * 2);
  h16* gh_e = (h16*)alloc((size_t)2048 * 1536 * 2);
  h16* msg_nb = (h16*)alloc(128 * 512 * 2);
  h16* msg_eb = (h16*)alloc(2048 * 512 * 2);
  h16* nm_e = (h16*)alloc(2048 * 512 * 2);
  int* elist = (int*)alloc(64 * 62 * 4);

  // ---- adaptive chunk scratch: prefer fewest chunks that fit ws ----
  const long tiers[6] = {1984, 992, 496, 248, 124, 62};
  const int tierz[6] = {2, 2, 4, 8, 8, 8};
  long CG = 0;
  int Z = 8;
  long M1cap = 0, P2R = 0;
  for (int t = 0; t < 6; ++t) {
    long cg = tiers[t];
    long m1 = ceil128(cg * 36);
    if (m1 < 2304) m1 = 2304;
    long p2r = ceil128(cg * 4);
    if (p2r < 256) p2r = 256;
    size_t chunkB = (size_t)m1 * 512 * 2 + (size_t)m1 * 1024 * 2 +
                    (size_t)p2r * 4096 * 2 +
                    (size_t)p2r * 512 * 4 * tierz[t] + 2048;
    if (cur + chunkB <= ws_size) {
      CG = cg; Z = tierz[t]; M1cap = m1; P2R = p2r;
      break;
    }
  }
  if (!CG) {
    diag_kernel<<<(out_size + 255) / 256, 256, 0, stream>>>(
        (float*)d_out, out_size, (float)((double)ws_size * 1e-6));
    return;
  }
  h16* P1 = (h16*)alloc((size_t)M1cap * 512 * 2);
  h16* C1 = (h16*)alloc((size_t)M1cap * 1024 * 2);
  h16* P2 = (h16*)alloc((size_t)P2R * 4096 * 2);
  float* C2 = (float*)alloc((size_t)P2R * 512 * 4 * Z);

  // ---- weight conversion (one fused launch) ----
  Cvt8 cj;
  const float* srcs[8] = {ncw1, ecw1, ncw2, ecw2, nwih, nwhh, ewih, ewhh};
  h16* dsts[8] = {W1rn, W1re, W2rn, W2re, Wihn, Whhn, Wihe, Whhe};
  long sizes[8] = {1024 * 512, 1024 * 512, (long)512 * 4096, (long)512 * 4096,
                   1536 * 512, 1536 * 512, 1536 * 512, 1536 * 512};
  long c = 0;
  for (int i = 0; i < 8; ++i) {
    cj.s[i] = srcs[i];
    cj.d[i] = dsts[i];
    cj.cum[i] = c;
    c += sizes[i];
  }
  cj.cum[8] = c;
  cvt8_kernel<<<(unsigned)((c + 255) / 256), 256, 0, stream>>>(cj);
  incid_kernel<<<16, 256, 0, stream>>>(eidx, elist, istride);

  // ---- CNN encoder (chunked) ----
  auto encoder = [&](const float* x, const h16* W1, const float* b1,
                     const h16* W2, const float* b2, h16* featb, long G,
                     long cg, int z) {
    for (long g0 = 0; g0 < G; g0 += cg) {
      long m1 = ceil128(cg * 36);
      long m2 = ceil128(cg * 4);
      im2col1_kernel<<<(unsigned)(cg * 36), 256, 0, stream>>>(
          x + g0 * 128 * 49, P1);
      gemm_bt<1, false><<<(unsigned)((m1 >> 7) * 8), 256, 0, stream>>>(
          P1, W1, C1, b1, nullptr, nullptr, nullptr, nullptr, (int)m1, 1024,
          512, 16);
      pool1_kernel<<<(unsigned)(cg * 64), 256, 0, stream>>>(C1, P2);
      gemm_bt<0, false><<<dim3((unsigned)((m2 >> 7) * 4), 1, z), 256, 0,
                          stream>>>(P2, W2, C2, nullptr, nullptr, nullptr,
                                    nullptr, nullptr, (int)m2, 512, 4096,
                                    128 / z);
      pool2_kernel<<<(unsigned)(cg * 2), 256, 0, stream>>>(
          C2, m2 * 512L, z, b2, featb + g0 * 512, (int)cg);
    }
  };
  encoder(node_lat, W1rn, ncb1, W2rn, ncb2, featbn, 64, 64, 8);
  encoder(edge_lat, W1re, ecb1, W2re, ecb2, featbe, 1984, CG, Z);

  // ---- initial GRU (h = 0) ----
  gemm_bt<2, false><<<12, 256, 0, stream>>>(
      featbn, Wihn, gi_n, nbih, nullptr, nullptr, nullptr, nullptr, 128, 1536,
      512, 16);
  gru_init_kernel<<<128, 256, 0, stream>>>(gi_n, nbhh, h_n, h_nb);
  gemm_bt<2, false><<<16 * 12, 256, 0, stream>>>(
      featbe, Wihe, gi_e, ebih, nullptr, nullptr, nullptr, nullptr, 2048, 1536,
      512, 16);
  gru_init_kernel<<<3968, 256, 0, stream>>>(gi_e, ebhh, h_e, h_eb);

  // ---- 2 message-passing iterations (ref's 3rd iteration output is dead) ----
  for (int it = 0; it < 2; ++it) {
    message_kernel<<<496, 256, 0, stream>>>(h_n, h_e, eidx, wnp, wps, wpo,
                                            msg_eb, nm_e, istride);
    gather_kernel<<<64, 256, 0, stream>>>(nm_e, elist, msg_nb);
    gemm_bt<2, true><<<dim3(12, 2), 256, 0, stream>>>(
        msg_nb, Wihn, gi_n, nbih, h_nb, Whhn, gh_n, nbhh, 128, 1536, 512, 16);
    gemm_bt<2, true><<<dim3(16 * 12, 2), 256, 0, stream>>>(
        msg_eb, Wihe, gi_e, ebih, h_eb, Whhe, gh_e, ebhh, 2048, 1536, 512, 16);
    gru_step_kernel<<<128, 256, 0, stream>>>(gi_n, gh_n, h_n, h_nb);
    gru_step_kernel<<<3968, 256, 0, stream>>>(gi_e, gh_e, h_e, h_eb);
  }

  // ---- output: nh (64x512) then eh (1984x512), both f32 ----
  out_kernel<<<4096, 256, 0, stream>>>(h_n, h_e, (float*)d_out);
}

// Round 4
// 528.822 us; speedup vs baseline: 1.8090x; 1.2000x over previous
//
#include <hip/hip_runtime.h>
#include <cstdint>
#include <cstddef>

typedef _Float16 h16;
typedef _Float16 h16x2 __attribute__((ext_vector_type(2)));
typedef _Float16 h16x4 __attribute__((ext_vector_type(4)));
typedef _Float16 h16x8 __attribute__((ext_vector_type(8)));
typedef float f32x4 __attribute__((ext_vector_type(4)));

typedef const uint32_t GU32 __attribute__((address_space(1)));
typedef uint32_t LU32 __attribute__((address_space(3)));

__device__ __forceinline__ void gload_lds16(const void* g, void* l) {
  __builtin_amdgcn_global_load_lds((GU32*)g, (LU32*)l, 16, 0, 0);
}

__device__ __forceinline__ float sigm(float x) { return 1.f / (1.f + __expf(-x)); }

static inline long ceil128(long x) { return (x + 127) & ~127L; }

// ---------------------------------------------------------------------------
// GEMM: C(M,N) = A(M,K) @ Bt(N,K)^T, fp16 in, fp32 accumulate (MFMA 16x16x32).
// m97 structure: 128x128 tile, BK=32, 4 waves, global_load_lds width 16.
// XCD-aware bijective work swizzle (m204): consecutive work ids (which share
// an A panel, since work = bm*ntn + bn) land on the SAME XCD's L2.
// EPI: 0 = raw f32 (split-K partial, C offset by blockIdx.z*M*N)
//      1 = +bias, ReLU, fp16 out
//      2 = +bias, fp16 out
// DUAL: blockIdx.y==1 selects second problem (same M,N,K).
// ---------------------------------------------------------------------------
template <int EPI, bool DUAL>
__global__ __launch_bounds__(256) void gemm_bt(
    const h16* __restrict__ A, const h16* __restrict__ Bt, void* Cv,
    const float* __restrict__ bias, const h16* A2, const h16* Bt2, void* Cv2,
    const float* bias2, int M, int N, int K, int nktSplit) {
  if (DUAL && blockIdx.y == 1) { A = A2; Bt = Bt2; Cv = Cv2; bias = bias2; }
  __shared__ __align__(16) h16 As[4096];
  __shared__ __align__(16) h16 Bs[4096];
  const int tid = threadIdx.x;
  const int lane = tid & 63;
  const int w = tid >> 6;
  const int ntn = N >> 7;
  // bijective XCD swizzle: hw id -> work id, contiguous work per XCD
  const int nwg = gridDim.x;
  const int q8 = nwg >> 3, r8 = nwg & 7;
  const int xcd = blockIdx.x & 7, loc = blockIdx.x >> 3;
  const int wg = (xcd < r8 ? xcd * (q8 + 1) : r8 * (q8 + 1) + (xcd - r8) * q8) + loc;
  const int bm = wg / ntn;
  const int bn = wg - bm * ntn;
  const long m0 = (long)bm << 7;
  const long n0 = (long)bn << 7;
  const int wm = w >> 1, wn = w & 1;

  f32x4 acc[4][4] = {};

  const int srow = (w << 4) + (lane >> 2);
  const int skoff = (lane & 3) << 3;
  const h16* Ag = A + (m0 + srow) * K + skoff;
  const h16* Bg = Bt + (n0 + srow) * K + skoff;
  h16* AsW = &As[w << 9];
  h16* BsW = &Bs[w << 9];
  const int lr = lane & 15;
  const int kg = lane >> 4;
  const h16* Ard = &As[((wm << 6) + lr) * 32 + (kg << 3)];
  const h16* Brd = &Bs[((wn << 6) + lr) * 32 + (kg << 3)];

  const int kt0 = blockIdx.z * nktSplit;
  for (int kt = kt0; kt < kt0 + nktSplit; ++kt) {
    const h16* a = Ag + (long)kt * 32;
    const h16* b = Bg + (long)kt * 32;
    gload_lds16(a, AsW);
    gload_lds16(a + (long)64 * K, AsW + 2048);
    gload_lds16(b, BsW);
    gload_lds16(b + (long)64 * K, BsW + 2048);
    __syncthreads();
    h16x8 af[4], bfr[4];
#pragma unroll
    for (int f = 0; f < 4; ++f) {
      af[f] = *(const h16x8*)(Ard + (f << 9));
      bfr[f] = *(const h16x8*)(Brd + (f << 9));
    }
#pragma unroll
    for (int fm = 0; fm < 4; ++fm)
#pragma unroll
      for (int fn = 0; fn < 4; ++fn)
        acc[fm][fn] = __builtin_amdgcn_mfma_f32_16x16x32_f16(af[fm], bfr[fn],
                                                             acc[fm][fn], 0, 0, 0);
    __syncthreads();
  }

  float* Cf = (float*)Cv;
  if (EPI == 0) Cf += (long)blockIdx.z * M * N;
  h16* Ch = (h16*)Cv;
#pragma unroll
  for (int fm = 0; fm < 4; ++fm)
#pragma unroll
    for (int fn = 0; fn < 4; ++fn)
#pragma unroll
      for (int j = 0; j < 4; ++j) {
        long row = m0 + (wm << 6) + (fm << 4) + (kg << 2) + j;
        long col = n0 + (wn << 6) + (fn << 4) + lr;
        float v = acc[fm][fn][j];
        if (EPI == 0) {
          Cf[row * N + col] = v;
        } else {
          v += bias[col];
          if (EPI == 1) v = fmaxf(v, 0.f);
          Ch[row * N + col] = (h16)v;
        }
      }
}

// ---------------------------------------------------------------------------
// im2col for conv1 (LDS-staged): block per image. x (128,7,7) f32 staged in
// LDS (25 KB, coalesced), then 16B-vector stores of P rows.
// P[(g*36+p)*512 + k], k = ch*4 + ky*2 + kx.
// ---------------------------------------------------------------------------
__global__ void im2col1_kernel(const float* __restrict__ x, h16* __restrict__ P) {
  __shared__ float xl[6272];
  const int g = blockIdx.x;
  const int tid = threadIdx.x;
  const float* src = x + (long)g * 6272;
  for (int i = tid; i < 6272; i += 256) xl[i] = src[i];
  __syncthreads();
  h16* dst = P + (long)g * 36 * 512;
  for (int item = tid; item < 36 * 64; item += 256) {
    int p = item >> 6;        // 0..35
    int k8 = item & 63;       // ch-pair
    int py = p / 6, px = p - py * 6;
    h16x8 v;
#pragma unroll
    for (int ci = 0; ci < 2; ++ci) {
      int base = (k8 * 2 + ci) * 49 + py * 7 + px;
      v[ci * 4 + 0] = (h16)xl[base];
      v[ci * 4 + 1] = (h16)xl[base + 1];
      v[ci * 4 + 2] = (h16)xl[base + 7];
      v[ci * 4 + 3] = (h16)xl[base + 8];
    }
    *(h16x8*)(dst + (long)p * 512 + k8 * 8) = v;
  }
}

// ---------------------------------------------------------------------------
// pool1 + im2col for conv2, vectorized. C1 (CG*36, 1024) fp16 (relu'd) ->
// P2 (CG*4, 4096) in PERMUTED K order: k' = (ky*2+kx)*1024 + ch.
// Thread = (g, q=ky*2+kx, p2, c8): 4x h16x8 loads, fmax, 1x h16x8 store.
// ---------------------------------------------------------------------------
__global__ void pool1_kernel(const h16* __restrict__ C1, h16* __restrict__ P2) {
  long idx = (long)blockIdx.x * 256 + threadIdx.x;  // grid: CG*8
  int c8 = (int)(idx & 127);
  int p2 = (int)((idx >> 7) & 3);
  int q = (int)((idx >> 9) & 3);
  long g = idx >> 11;
  int ky = q >> 1, kx = q & 1;
  int yp = (p2 >> 1) + ky, xp = (p2 & 1) + kx;
  const h16* base = C1 + g * 36 * 1024 + c8 * 8;
  float mv[8] = {0, 0, 0, 0, 0, 0, 0, 0};  // relu'd inputs are >= 0
#pragma unroll
  for (int dy = 0; dy < 2; ++dy)
#pragma unroll
    for (int dx = 0; dx < 2; ++dx) {
      int row = (2 * yp + dy) * 6 + (2 * xp + dx);
      h16x8 v = *(const h16x8*)(base + (long)row * 1024);
#pragma unroll
      for (int j = 0; j < 8; ++j) mv[j] = fmaxf(mv[j], (float)v[j]);
    }
  h16x8 o;
#pragma unroll
  for (int j = 0; j < 8; ++j) o[j] = (h16)mv[j];
  *(h16x8*)(P2 + (g * 4 + p2) * 4096 + q * 1024 + c8 * 8) = o;
}

// pool2 + bias + relu over split-K partial sums -> feat rows (fp16).
__global__ void pool2_kernel(const float* __restrict__ C2, long partStride,
                             int nparts, const float* __restrict__ bias,
                             h16* __restrict__ featb, int Gvalid) {
  long idx = (long)blockIdx.x * 256 + threadIdx.x;
  int o = (int)(idx & 511);
  long m = idx >> 9;
  if (m >= Gvalid) return;
  float s0 = 0, s1 = 0, s2 = 0, s3 = 0;
  for (int s = 0; s < nparts; ++s) {
    const float* bp = C2 + (long)s * partStride + m * 2048 + o;
    s0 += bp[0]; s1 += bp[512]; s2 += bp[1024]; s3 += bp[1536];
  }
  float v = fmaxf(fmaxf(s0, s1), fmaxf(s2, s3)) + bias[o];
  featb[idx] = (h16)fmaxf(v, 0.f);
}

// GRU with h=0: gh reduces to b_hh broadcast. Gates stored fp16.
__global__ void gru_init_kernel(const h16* __restrict__ gi,
                                const float* __restrict__ b_hh,
                                float* __restrict__ h, h16* __restrict__ hb) {
  long idx = (long)blockIdx.x * 256 + threadIdx.x;
  int j = (int)(idx & 511);
  long m = idx >> 9;
  const h16* g = gi + m * 1536;
  float r = sigm((float)g[j] + b_hh[j]);
  float z = sigm((float)g[512 + j] + b_hh[512 + j]);
  float n = tanhf((float)g[1024 + j] + r * b_hh[1024 + j]);
  float hv = (1.f - z) * n;
  h[idx] = hv;
  hb[idx] = (h16)hv;
}

__global__ void gru_step_kernel(const h16* __restrict__ gi,
                                const h16* __restrict__ gh,
                                float* __restrict__ h, h16* __restrict__ hb) {
  long idx = (long)blockIdx.x * 256 + threadIdx.x;
  int j = (int)(idx & 511);
  long m = idx >> 9;
  const h16* a = gi + m * 1536;
  const h16* b = gh + m * 1536;
  float r = sigm((float)a[j] + (float)b[j]);
  float z = sigm((float)a[512 + j] + (float)b[512 + j]);
  float n = tanhf((float)a[1024 + j] + r * (float)b[1024 + j]);
  float hv = (1.f - z) * n + z * h[idx];
  h[idx] = hv;
  hb[idx] = (h16)hv;
}

// Message kernel: one wave per edge row (re = b*992 + e).
__global__ void message_kernel(const float* __restrict__ h_n,
                               const float* __restrict__ h_e,
                               const int* __restrict__ eidx,
                               const float* __restrict__ wnp,
                               const float* __restrict__ wps,
                               const float* __restrict__ wpo,
                               h16* __restrict__ msg_eb,
                               h16* __restrict__ nm_e, int istride) {
  int re = blockIdx.x * 4 + (threadIdx.x >> 6);
  int lane = threadIdx.x & 63;
  int b = re / 992;
  int e = re - b * 992;
  long base = ((long)b * 992 + e) * 3;
  int s = eidx[(base + 1) * istride];
  int o = eidx[(base + 2) * istride];
  const float* ns = h_n + (long)(b * 32 + s) * 512;
  const float* no = h_n + (long)(b * 32 + o) * 512;
  const float* eh = h_e + (long)re * 512;
  float dn = 0, ds = 0, dob = 0;
  for (int t = lane; t < 512; t += 64) {
    float nsv = ns[t], nov = no[t], ehv = eh[t];
    dn += nsv * wnp[t] + ehv * wnp[512 + t];
    ds += nsv * wps[t] + ehv * wps[512 + t];
    dob += nov * wpo[t] + ehv * wpo[512 + t];
  }
#pragma unroll
  for (int off = 32; off; off >>= 1) {
    dn += __shfl_xor(dn, off);
    ds += __shfl_xor(ds, off);
    dob += __shfl_xor(dob, off);
  }
  float sn = sigm(dn), ss = sigm(ds), so = sigm(dob);
  for (int t = lane; t < 512; t += 64) {
    msg_eb[(long)re * 512 + t] = (h16)(ss * ns[t] + so * no[t]);
    nm_e[(long)re * 512 + t] = (h16)(sn * eh[t]);
  }
}

// Incidence build: per (b,n), ordered list of 31 subj-edges then 31 obj-edges.
__global__ void incid_kernel(const int* __restrict__ eidx,
                             int* __restrict__ elist, int istride) {
  int w = (blockIdx.x << 2) + (threadIdx.x >> 6);  // 16 blocks * 4 waves = 64
  int lane = threadIdx.x & 63;
  int b = w >> 5, n = w & 31;
  const int* eb = eidx + (long)b * 992 * 3 * istride;
  int* dst = elist + w * 62;
  int bs = 0, bo = 0;
  for (int c = 0; c < 16; ++c) {
    int e = c * 64 + lane;
    bool v = e < 992;
    int s = v ? eb[(e * 3 + 1) * istride] : -1;
    int o = v ? eb[(e * 3 + 2) * istride] : -1;
    unsigned long long ms = __ballot(s == n);
    unsigned long long mo = __ballot(o == n);
    unsigned long long below = (1ull << lane) - 1ull;
    if (s == n) {
      int p = bs + __popcll(ms & below);
      if (p < 31) dst[p] = e;
    }
    if (o == n) {
      int p = bo + __popcll(mo & below);
      if (p < 31) dst[31 + p] = e;
    }
    bs += __popcll(ms);
    bo += __popcll(mo);
  }
  for (int i = bs + lane; i < 31; i += 64) dst[i] = -1;
  for (int i = bo + lane; i < 31; i += 64) dst[31 + i] = -1;
}

// Node-message gather via incidence lists: block per (b,n), 62 edge rows.
__global__ void gather_kernel(const h16* __restrict__ nm_e,
                              const int* __restrict__ elist,
                              h16* __restrict__ msg_nb) {
  int bn = blockIdx.x;  // 64
  int t = threadIdx.x;  // 256
  int b = bn >> 5;
  const int* lst = elist + bn * 62;
  float a0 = 0.f, a1 = 0.f;
#pragma unroll 2
  for (int i = 0; i < 62; ++i) {
    int e = lst[i];
    if (e < 0) continue;
    h16x2 v = *(const h16x2*)(nm_e + ((long)b * 992 + e) * 512 + t * 2);
    a0 += (float)v.x;
    a1 += (float)v.y;
  }
  h16* d = msg_nb + (long)bn * 512 + t * 2;
  d[0] = (h16)a0;
  d[1] = (h16)a1;
}

// Fused f32->fp16 conversion of all 8 weight matrices. perm[seg]==1 applies
// the conv2 K-permutation k' = q*1024 + ch  (from k = ch*4 + q).
struct Cvt8 {
  const float* s[8];
  h16* d[8];
  long cum[9];
  int perm[8];
};
__global__ void cvt8_kernel(Cvt8 j) {
  long idx = (long)blockIdx.x * 256 + threadIdx.x;
  if (idx >= j.cum[8]) return;
  int seg = 0;
  while (idx >= j.cum[seg + 1]) ++seg;
  long off = idx - j.cum[seg];
  long soff = off;
  if (j.perm[seg]) {
    long o = off >> 12;
    long rest = off & 4095;
    long q = rest >> 10;
    long ch = rest & 1023;
    soff = o * 4096 + ch * 4 + q;
  }
  j.d[seg][off] = (h16)j.s[seg][soff];
}

__global__ void out_kernel(const float* __restrict__ h_n,
                           const float* __restrict__ h_e,
                           float* __restrict__ out) {
  long i = (long)blockIdx.x * 256 + threadIdx.x;  // 1048576 total
  out[i] = (i < 32768) ? h_n[i] : h_e[i - 32768];
}

// ws-too-small diagnostic: zero output, out[0] encodes ws_size in MB.
__global__ void diag_kernel(float* out, int n, float v) {
  int i = blockIdx.x * 256 + threadIdx.x;
  if (i < n) out[i] = (i == 0) ? v : 0.f;
}

// ---------------------------------------------------------------------------
extern "C" void kernel_launch(void* const* d_in, const int* in_sizes, int n_in,
                              void* d_out, int out_size, void* d_ws,
                              size_t ws_size, hipStream_t stream) {
  const float* node_lat = (const float*)d_in[0];
  const float* edge_lat = (const float*)d_in[1];
  const int* eidx = (const int*)d_in[2];
  const float* ncw1 = (const float*)d_in[3];
  const float* ncb1 = (const float*)d_in[4];
  const float* ncw2 = (const float*)d_in[5];
  const float* ncb2 = (const float*)d_in[6];
  const float* ecw1 = (const float*)d_in[7];
  const float* ecb1 = (const float*)d_in[8];
  const float* ecw2 = (const float*)d_in[9];
  const float* ecb2 = (const float*)d_in[10];
  const float* nwih = (const float*)d_in[11];
  const float* nwhh = (const float*)d_in[12];
  const float* nbih = (const float*)d_in[13];
  const float* nbhh = (const float*)d_in[14];
  const float* ewih = (const float*)d_in[15];
  const float* ewhh = (const float*)d_in[16];
  const float* ebih = (const float*)d_in[17];
  const float* ebhh = (const float*)d_in[18];
  const float* wnp = (const float*)d_in[19];
  const float* wps = (const float*)d_in[20];
  const float* wpo = (const float*)d_in[21];

  const int istride = (in_sizes[2] == 2 * 992 * 3 * 2) ? 2 : 1;

  char* wsb = (char*)d_ws;
  size_t cur = 0;
  auto alloc = [&](size_t b) -> char* {
    char* p = wsb + cur;
    cur += (b + 255) & ~(size_t)255;
    return p;
  };

  // ---- fixed region (~43.5 MB) ----
  h16* W1rn = (h16*)alloc(1024 * 512 * 2);
  h16* W1re = (h16*)alloc(1024 * 512 * 2);
  h16* W2rn = (h16*)alloc((size_t)512 * 4096 * 2);
  h16* W2re = (h16*)alloc((size_t)512 * 4096 * 2);
  h16* Wihn = (h16*)alloc(1536 * 512 * 2);
  h16* Whhn = (h16*)alloc(1536 * 512 * 2);
  h16* Wihe = (h16*)alloc(1536 * 512 * 2);
  h16* Whhe = (h16*)alloc(1536 * 512 * 2);
  h16* featbn = (h16*)alloc(128 * 512 * 2);
  h16* featbe = (h16*)alloc(2048 * 512 * 2);
  float* h_n = (float*)alloc(128 * 512 * 4);
  h16* h_nb = (h16*)alloc(128 * 512 * 2);
  float* h_e = (float*)alloc(2048 * 512 * 4);
  h16* h_eb = (h16*)alloc(2048 * 512 * 2);
  h16* gi_n = (h16*)alloc(128 * 1536 * 2);
  h16* gh_n = (h16*)alloc(128 * 1536 * 2);
  h16* gi_e = (h16*)alloc((size_t)2048 * 1536 * 2);
  h16* gh_e = (h16*)alloc((size_t)2048 * 1536 * 2);
  h16* msg_nb = (h16*)alloc(128 * 512 * 2);
  h16* msg_eb = (h16*)alloc(2048 * 512 * 2);
  h16* nm_e = (h16*)alloc(2048 * 512 * 2);
  int* elist = (int*)alloc(64 * 62 * 4);

  // ---- adaptive chunk scratch: prefer fewest chunks / most split-K ----
  const long tiers[7] = {1984, 992, 992, 496, 248, 124, 62};
  const int tierz[7] = {4, 4, 2, 4, 8, 8, 8};
  long CG = 0;
  int Z = 8;
  long M1cap = 0, P2R = 0;
  for (int t = 0; t < 7; ++t) {
    long cg = tiers[t];
    long m1 = ceil128(cg * 36);
    if (m1 < 2304) m1 = 2304;
    long p2r = ceil128(cg * 4);
    if (p2r < 256) p2r = 256;
    size_t zmax = tierz[t] > 8 ? tierz[t] : 8;  // node encoder uses z=8
    size_t chunkB = (size_t)m1 * 512 * 2 + (size_t)m1 * 1024 * 2 +
                    (size_t)p2r * 4096 * 2 +
                    (size_t)(p2r > 256 ? p2r * tierz[t] : 256 * 8) * 512 * 4 +
                    4096;
    (void)zmax;
    if (cur + chunkB <= ws_size) {
      CG = cg; Z = tierz[t]; M1cap = m1; P2R = p2r;
      break;
    }
  }
  if (!CG) {
    diag_kernel<<<(out_size + 255) / 256, 256, 0, stream>>>(
        (float*)d_out, out_size, (float)((double)ws_size * 1e-6));
    return;
  }
  size_t c2parts = (size_t)(P2R > 256 ? P2R * Z : 256 * 8);
  h16* P1 = (h16*)alloc((size_t)M1cap * 512 * 2);
  h16* C1 = (h16*)alloc((size_t)M1cap * 1024 * 2);
  h16* P2 = (h16*)alloc((size_t)P2R * 4096 * 2);
  float* C2 = (float*)alloc(c2parts * 512 * 4);

  // ---- weight conversion (one fused launch; W2 gets K-permuted) ----
  Cvt8 cj;
  const float* srcs[8] = {ncw1, ecw1, ncw2, ecw2, nwih, nwhh, ewih, ewhh};
  h16* dsts[8] = {W1rn, W1re, W2rn, W2re, Wihn, Whhn, Wihe, Whhe};
  long sizes[8] = {1024 * 512, 1024 * 512, (long)512 * 4096, (long)512 * 4096,
                   1536 * 512, 1536 * 512, 1536 * 512, 1536 * 512};
  int perms[8] = {0, 0, 1, 1, 0, 0, 0, 0};
  long c = 0;
  for (int i = 0; i < 8; ++i) {
    cj.s[i] = srcs[i];
    cj.d[i] = dsts[i];
    cj.cum[i] = c;
    cj.perm[i] = perms[i];
    c += sizes[i];
  }
  cj.cum[8] = c;
  cvt8_kernel<<<(unsigned)((c + 255) / 256), 256, 0, stream>>>(cj);
  incid_kernel<<<16, 256, 0, stream>>>(eidx, elist, istride);

  // ---- CNN encoder (chunked) ----
  auto encoder = [&](const float* x, const h16* W1, const float* b1,
                     const h16* W2, const float* b2, h16* featb, long G,
                     long cg, int z) {
    for (long g0 = 0; g0 < G; g0 += cg) {
      long m1 = ceil128(cg * 36);
      long m2 = ceil128(cg * 4);
      im2col1_kernel<<<(unsigned)cg, 256, 0, stream>>>(x + g0 * 128 * 49, P1);
      gemm_bt<1, false><<<(unsigned)((m1 >> 7) * 8), 256, 0, stream>>>(
          P1, W1, C1, b1, nullptr, nullptr, nullptr, nullptr, (int)m1, 1024,
          512, 16);
      pool1_kernel<<<(unsigned)(cg * 8), 256, 0, stream>>>(C1, P2);
      gemm_bt<0, false><<<dim3((unsigned)((m2 >> 7) * 4), 1, z), 256, 0,
                          stream>>>(P2, W2, C2, nullptr, nullptr, nullptr,
                                    nullptr, nullptr, (int)m2, 512, 4096,
                                    128 / z);
      pool2_kernel<<<(unsigned)(cg * 2), 256, 0, stream>>>(
          C2, m2 * 512L, z, b2, featb + g0 * 512, (int)cg);
    }
  };
  encoder(node_lat, W1rn, ncb1, W2rn, ncb2, featbn, 64, 64, 8);
  encoder(edge_lat, W1re, ecb1, W2re, ecb2, featbe, 1984, CG, Z);

  // ---- initial GRU (h = 0) ----
  gemm_bt<2, false><<<12, 256, 0, stream>>>(
      featbn, Wihn, gi_n, nbih, nullptr, nullptr, nullptr, nullptr, 128, 1536,
      512, 16);
  gru_init_kernel<<<128, 256, 0, stream>>>(gi_n, nbhh, h_n, h_nb);
  gemm_bt<2, false><<<16 * 12, 256, 0, stream>>>(
      featbe, Wihe, gi_e, ebih, nullptr, nullptr, nullptr, nullptr, 2048, 1536,
      512, 16);
  gru_init_kernel<<<3968, 256, 0, stream>>>(gi_e, ebhh, h_e, h_eb);

  // ---- 2 message-passing iterations (ref's 3rd iteration output is dead) ----
  for (int it = 0; it < 2; ++it) {
    message_kernel<<<496, 256, 0, stream>>>(h_n, h_e, eidx, wnp, wps, wpo,
                                            msg_eb, nm_e, istride);
    gather_kernel<<<64, 256, 0, stream>>>(nm_e, elist, msg_nb);
    gemm_bt<2, true><<<dim3(12, 2), 256, 0, stream>>>(
        msg_nb, Wihn, gi_n, nbih, h_nb, Whhn, gh_n, nbhh, 128, 1536, 512, 16);
    gemm_bt<2, true><<<dim3(16 * 12, 2), 256, 0, stream>>>(
        msg_eb, Wihe, gi_e, ebih, h_eb, Whhe, gh_e, ebhh, 2048, 1536, 512, 16);
    gru_step_kernel<<<128, 256, 0, stream>>>(gi_n, gh_n, h_n, h_nb);
    gru_step_kernel<<<3968, 256, 0, stream>>>(gi_e, gh_e, h_e, h_eb);
  }

  // ---- output: nh (64x512) then eh (1984x512), both f32 ----
  out_kernel<<<4096, 256, 0, stream>>>(h_n, h_e, (float*)d_out);
}

// Round 6
// 494.754 us; speedup vs baseline: 1.9336x; 1.0689x over previous
//
#include <hip/hip_runtime.h>
#include <cstdint>
#include <cstddef>

typedef _Float16 h16;
typedef _Float16 h16x2 __attribute__((ext_vector_type(2)));
typedef _Float16 h16x8 __attribute__((ext_vector_type(8)));
typedef float f32x4 __attribute__((ext_vector_type(4)));

typedef const uint32_t GU32 __attribute__((address_space(1)));
typedef uint32_t LU32 __attribute__((address_space(3)));

__device__ __forceinline__ void gload_lds16(const void* g, void* l) {
  __builtin_amdgcn_global_load_lds((GU32*)g, (LU32*)l, 16, 0, 0);
}

__device__ __forceinline__ float sigm(float x) { return 1.f / (1.f + __expf(-x)); }

static inline long ceil128(long x) { return (x + 127) & ~127L; }

// ---------------------------------------------------------------------------
// GEMM: C(M,N) = A(M,K) @ Bt(N,K)^T, fp16 in, fp32 acc (MFMA 16x16x32).
// 128x128 tile, BK=32, 4 waves, global_load_lds w16, XCD-bijective swizzle.
// Per-block weight switch at bm >= bmSwitch (part 0 -> part 1): lets one
// launch cover concatenated node/edge row blocks (boundary = 0 mod 128).
// NY=2: blockIdx.y selects (A,C,weights) problem (gi vs gh).
// EPI: 0 = raw f32 split-K partial (C + z*M*N); 1 = bias+ReLU fp16;
//      2 = bias fp16.  EPI 1/2 use an LDS-repack epilogue for coalesced
//      h16x8 stores (the scalar-store epilogue was ~40% of kernel time).
// ---------------------------------------------------------------------------
struct GemmP {
  const h16* A[2];
  const h16* Bt[2][2];
  void* C[2];
  const float* bias[2][2];
  int M, N, K, nkt, bmSwitch;
};

template <int EPI, int NY>
__global__ __launch_bounds__(256) void gemm_bt(GemmP P) {
  const int y = (NY == 2) ? blockIdx.y : 0;
  __shared__ __align__(16) h16 SH[8192];
  h16* As = SH;
  h16* Bs = SH + 4096;
  const int tid = threadIdx.x;
  const int lane = tid & 63;
  const int w = tid >> 6;
  const int ntn = P.N >> 7;
  const int nwg = gridDim.x;
  const int q8 = nwg >> 3, r8 = nwg & 7;
  const int xcd = blockIdx.x & 7, loc = blockIdx.x >> 3;
  const int wg = (xcd < r8 ? xcd * (q8 + 1) : r8 * (q8 + 1) + (xcd - r8) * q8) + loc;
  const int bm = wg / ntn;
  const int bn = wg - bm * ntn;
  const int part = (bm >= P.bmSwitch) ? 1 : 0;
  const h16* __restrict__ A = P.A[y];
  const h16* __restrict__ Bt = P.Bt[y][part];
  const float* __restrict__ bias = P.bias[y][part];
  const long m0 = (long)bm << 7;
  const long n0 = (long)bn << 7;
  const int wm = w >> 1, wn = w & 1;

  f32x4 acc[4][4] = {};

  const int srow = (w << 4) + (lane >> 2);
  const int skoff = (lane & 3) << 3;
  const h16* Ag = A + (m0 + srow) * P.K + skoff;
  const h16* Bg = Bt + (n0 + srow) * P.K + skoff;
  h16* AsW = As + (w << 9);
  h16* BsW = Bs + (w << 9);
  const int lr = lane & 15;
  const int kg = lane >> 4;
  const h16* Ard = As + ((wm << 6) + lr) * 32 + (kg << 3);
  const h16* Brd = Bs + ((wn << 6) + lr) * 32 + (kg << 3);

  const int kt0 = blockIdx.z * P.nkt;
  for (int kt = kt0; kt < kt0 + P.nkt; ++kt) {
    const h16* a = Ag + (long)kt * 32;
    const h16* b = Bg + (long)kt * 32;
    gload_lds16(a, AsW);
    gload_lds16(a + (long)64 * P.K, AsW + 2048);
    gload_lds16(b, BsW);
    gload_lds16(b + (long)64 * P.K, BsW + 2048);
    __syncthreads();
    h16x8 af[4], bfr[4];
#pragma unroll
    for (int f = 0; f < 4; ++f) {
      af[f] = *(const h16x8*)(Ard + (f << 9));
      bfr[f] = *(const h16x8*)(Brd + (f << 9));
    }
#pragma unroll
    for (int fm = 0; fm < 4; ++fm)
#pragma unroll
      for (int fn = 0; fn < 4; ++fn)
        acc[fm][fn] = __builtin_amdgcn_mfma_f32_16x16x32_f16(af[fm], bfr[fn],
                                                             acc[fm][fn], 0, 0, 0);
    __syncthreads();
  }

  if (EPI == 0) {
    float* Cf = (float*)P.C[y] + (long)blockIdx.z * P.M * P.N;
#pragma unroll
    for (int fm = 0; fm < 4; ++fm)
#pragma unroll
      for (int fn = 0; fn < 4; ++fn)
#pragma unroll
        for (int j = 0; j < 4; ++j) {
          long row = m0 + (wm << 6) + (fm << 4) + (kg << 2) + j;
          long col = n0 + (wn << 6) + (fn << 4) + lr;
          Cf[row * P.N + col] = acc[fm][fn][j];
        }
  } else {
    // LDS-repack epilogue: pass p stores cols [p*64, p*64+64) of the tile.
    h16* Ch = (h16*)P.C[y];
#pragma unroll
    for (int pass = 0; pass < 2; ++pass) {
      if (pass) __syncthreads();  // prior pass reads done
      if (wn == pass) {
#pragma unroll
        for (int fm = 0; fm < 4; ++fm)
#pragma unroll
          for (int fn = 0; fn < 4; ++fn)
#pragma unroll
            for (int j = 0; j < 4; ++j) {
              int lrow = (wm << 6) + (fm << 4) + (kg << 2) + j;  // 0..127
              int lcol = (fn << 4) + lr;                         // 0..63
              float v = acc[fm][fn][j] + bias[n0 + (wn << 6) + lcol];
              if (EPI == 1) v = fmaxf(v, 0.f);
              int cc = (lcol >> 3) ^ (lrow & 7);  // bank swizzle
              SH[lrow * 64 + cc * 8 + (lcol & 7)] = (h16)v;
            }
      }
      __syncthreads();
      // 256 threads: 8 threads/row -> 128B contiguous per row, 4 rounds
#pragma unroll
      for (int rr = 0; rr < 4; ++rr) {
        int row = (rr << 5) + (tid >> 3);
        int c = tid & 7;
        int cs = c ^ (row & 7);
        h16x8 v = *(const h16x8*)(SH + row * 64 + cs * 8);
        *(h16x8*)(Ch + (m0 + row) * P.N + n0 + (pass << 6) + (c << 3)) = v;
      }
    }
  }
}

// ---------------------------------------------------------------------------
// im2col for conv1 (LDS-staged): block per image; first nEdge images come
// from eSrc, the rest from nSrc. P[(g*36+p)*512 + ch*4+ky*2+kx].
// ---------------------------------------------------------------------------
__global__ void im2col1_kernel(const float* __restrict__ eSrc,
                               const float* __restrict__ nSrc, int nEdge,
                               h16* __restrict__ P) {
  __shared__ float xl[6272];
  const int g = blockIdx.x;
  const int tid = threadIdx.x;
  const float* src = (g < nEdge) ? eSrc + (long)g * 6272
                                 : nSrc + (long)(g - nEdge) * 6272;
  for (int i = tid; i < 6272; i += 256) xl[i] = src[i];
  __syncthreads();
  h16* dst = P + (long)g * 36 * 512;
  for (int item = tid; item < 36 * 64; item += 256) {
    int p = item >> 6;
    int k8 = item & 63;
    int py = p / 6, px = p - py * 6;
    h16x8 v;
#pragma unroll
    for (int ci = 0; ci < 2; ++ci) {
      int base = (k8 * 2 + ci) * 49 + py * 7 + px;
      v[ci * 4 + 0] = (h16)xl[base];
      v[ci * 4 + 1] = (h16)xl[base + 1];
      v[ci * 4 + 2] = (h16)xl[base + 7];
      v[ci * 4 + 3] = (h16)xl[base + 8];
    }
    *(h16x8*)(dst + (long)p * 512 + k8 * 8) = v;
  }
}

// pool1 + im2col for conv2 (K-permuted: k' = (ky*2+kx)*1024 + ch).
__global__ void pool1_kernel(const h16* __restrict__ C1, h16* __restrict__ P2) {
  long idx = (long)blockIdx.x * 256 + threadIdx.x;  // grid: imgs*8
  int c8 = (int)(idx & 127);
  int p2 = (int)((idx >> 7) & 3);
  int q = (int)((idx >> 9) & 3);
  long g = idx >> 11;
  int ky = q >> 1, kx = q & 1;
  int yp = (p2 >> 1) + ky, xp = (p2 & 1) + kx;
  const h16* base = C1 + g * 36 * 1024 + c8 * 8;
  float mv[8] = {0, 0, 0, 0, 0, 0, 0, 0};  // relu'd inputs >= 0
#pragma unroll
  for (int dy = 0; dy < 2; ++dy)
#pragma unroll
    for (int dx = 0; dx < 2; ++dx) {
      int row = (2 * yp + dy) * 6 + (2 * xp + dx);
      h16x8 v = *(const h16x8*)(base + (long)row * 1024);
#pragma unroll
      for (int j = 0; j < 8; ++j) mv[j] = fmaxf(mv[j], (float)v[j]);
    }
  h16x8 o;
#pragma unroll
  for (int j = 0; j < 8; ++j) o[j] = (h16)mv[j];
  *(h16x8*)(P2 + (g * 4 + p2) * 4096 + q * 1024 + c8 * 8) = o;
}

// pool2 + bias + relu over split-K partials -> concatenated feat rows.
// image g (chunk-local): edge (g<nEdge) -> feat row 128+e0+g, else node row g-nEdge.
__global__ void pool2_kernel(const float* __restrict__ C2, long partStride,
                             const float* __restrict__ biasE,
                             const float* __restrict__ biasN, int nEdge,
                             int e0, h16* __restrict__ featc) {
  long idx = (long)blockIdx.x * 256 + threadIdx.x;  // grid: imgs*2
  int o = (int)(idx & 511);
  long g = idx >> 9;
  float s0 = 0, s1 = 0, s2 = 0, s3 = 0;
  for (int s = 0; s < 4; ++s) {
    const float* bp = C2 + (long)s * partStride + g * 2048 + o;
    s0 += bp[0]; s1 += bp[512]; s2 += bp[1024]; s3 += bp[1536];
  }
  const float* bias = (g < nEdge) ? biasE : biasN;
  long row = (g < nEdge) ? 128 + e0 + g : g - nEdge;
  float v = fmaxf(fmaxf(s0, s1), fmaxf(s2, s3)) + bias[o];
  featc[row * 512 + o] = (h16)fmaxf(v, 0.f);
}

// GRU with h=0: gh reduces to b_hh broadcast. Concat rows (node<128, edge>=128).
__global__ void gru_init_kernel(const h16* __restrict__ gi,
                                const float* __restrict__ nbhh,
                                const float* __restrict__ ebhh,
                                float* __restrict__ h, h16* __restrict__ hb) {
  long idx = (long)blockIdx.x * 256 + threadIdx.x;  // grid 2176*2
  int j = (int)(idx & 511);
  long m = idx >> 9;
  const float* b_hh = (m < 128) ? nbhh : ebhh;
  const h16* g = gi + m * 1536;
  float r = sigm((float)g[j] + b_hh[j]);
  float z = sigm((float)g[512 + j] + b_hh[512 + j]);
  float n = tanhf((float)g[1024 + j] + r * b_hh[1024 + j]);
  float hv = (1.f - z) * n;
  h[idx] = hv;
  hb[idx] = (h16)hv;
}

__global__ void gru_step_kernel(const h16* __restrict__ gi,
                                const h16* __restrict__ gh,
                                float* __restrict__ h, h16* __restrict__ hb) {
  long idx = (long)blockIdx.x * 256 + threadIdx.x;  // grid 2176*2
  int j = (int)(idx & 511);
  long m = idx >> 9;
  const h16* a = gi + m * 1536;
  const h16* b = gh + m * 1536;
  float r = sigm((float)a[j] + (float)b[j]);
  float z = sigm((float)a[512 + j] + (float)b[512 + j]);
  float n = tanhf((float)a[1024 + j] + r * (float)b[1024 + j]);
  float hv = (1.f - z) * n + z * h[idx];
  h[idx] = hv;
  hb[idx] = (h16)hv;
}

// Message kernel: one wave per edge (re = b*992 + e). h rows: node b*32+n,
// edge 128+re. Writes msg_eb into msgc rows 128+re.
__global__ void message_kernel(const float* __restrict__ h,
                               const int* __restrict__ eidx,
                               const float* __restrict__ wnp,
                               const float* __restrict__ wps,
                               const float* __restrict__ wpo,
                               h16* __restrict__ msgc,
                               h16* __restrict__ nm_e, int istride) {
  int re = blockIdx.x * 4 + (threadIdx.x >> 6);
  int lane = threadIdx.x & 63;
  int b = re / 992;
  int e = re - b * 992;
  long base = ((long)b * 992 + e) * 3;
  int s = eidx[(base + 1) * istride];
  int o = eidx[(base + 2) * istride];
  const float* ns = h + (long)(b * 32 + s) * 512;
  const float* no = h + (long)(b * 32 + o) * 512;
  const float* eh = h + (long)(128 + re) * 512;
  float dn = 0, ds = 0, dob = 0;
  for (int t = lane; t < 512; t += 64) {
    float nsv = ns[t], nov = no[t], ehv = eh[t];
    dn += nsv * wnp[t] + ehv * wnp[512 + t];
    ds += nsv * wps[t] + ehv * wps[512 + t];
    dob += nov * wpo[t] + ehv * wpo[512 + t];
  }
#pragma unroll
  for (int off = 32; off; off >>= 1) {
    dn += __shfl_xor(dn, off);
    ds += __shfl_xor(ds, off);
    dob += __shfl_xor(dob, off);
  }
  float sn = sigm(dn), ss = sigm(ds), so = sigm(dob);
  for (int t = lane; t < 512; t += 64) {
    msgc[(long)(128 + re) * 512 + t] = (h16)(ss * ns[t] + so * no[t]);
    nm_e[(long)re * 512 + t] = (h16)(sn * eh[t]);
  }
}

// Incidence build: per (b,n), ordered 31 subj then 31 obj edge ids (batch-local).
__global__ void incid_kernel(const int* __restrict__ eidx,
                             int* __restrict__ elist, int istride) {
  int w = (blockIdx.x << 2) + (threadIdx.x >> 6);  // 64 waves
  int lane = threadIdx.x & 63;
  int b = w >> 5, n = w & 31;
  const int* eb = eidx + (long)b * 992 * 3 * istride;
  int* dst = elist + w * 62;
  int bs = 0, bo = 0;
  for (int c = 0; c < 16; ++c) {
    int e = c * 64 + lane;
    bool v = e < 992;
    int s = v ? eb[(e * 3 + 1) * istride] : -1;
    int o = v ? eb[(e * 3 + 2) * istride] : -1;
    unsigned long long ms = __ballot(s == n);
    unsigned long long mo = __ballot(o == n);
    unsigned long long below = (1ull << lane) - 1ull;
    if (s == n) {
      int p = bs + __popcll(ms & below);
      if (p < 31) dst[p] = e;
    }
    if (o == n) {
      int p = bo + __popcll(mo & below);
      if (p < 31) dst[31 + p] = e;
    }
    bs += __popcll(ms);
    bo += __popcll(mo);
  }
  for (int i = bs + lane; i < 31; i += 64) dst[i] = -1;
  for (int i = bo + lane; i < 31; i += 64) dst[31 + i] = -1;
}

// Node-message gather via incidence lists -> msgc rows 0..63.
// elist holds BATCH-LOCAL edge ids; nm_e row = b*992 + e.  (R5 bug: b*992
// offset was missing -> batch 1 gathered batch 0's messages.)
__global__ void gather_kernel(const h16* __restrict__ nm_e,
                              const int* __restrict__ elist,
                              h16* __restrict__ msgc) {
  int bn = blockIdx.x;  // 64
  int t = threadIdx.x;  // 256
  int b = bn >> 5;
  const int* lst = elist + bn * 62;
  const h16* nmb = nm_e + (long)b * 992 * 512;
  float a0 = 0.f, a1 = 0.f;
#pragma unroll 2
  for (int i = 0; i < 62; ++i) {
    int e = lst[i];
    if (e < 0) continue;
    h16x2 v = *(const h16x2*)(nmb + (long)e * 512 + t * 2);
    a0 += (float)v.x;
    a1 += (float)v.y;
  }
  h16* d = msgc + (long)bn * 512 + t * 2;
  d[0] = (h16)a0;
  d[1] = (h16)a1;
}

// Fused f32->fp16 conversion of all 8 weight mats (W2 gets K-permute).
struct Cvt8 {
  const float* s[8];
  h16* d[8];
  long cum[9];
  int perm[8];
};
__global__ void cvt8_kernel(Cvt8 j) {
  long idx = (long)blockIdx.x * 256 + threadIdx.x;
  if (idx >= j.cum[8]) return;
  int seg = 0;
  while (idx >= j.cum[seg + 1]) ++seg;
  long off = idx - j.cum[seg];
  long soff = off;
  if (j.perm[seg]) {
    long o = off >> 12;
    long rest = off & 4095;
    long q = rest >> 10;
    long ch = rest & 1023;
    soff = o * 4096 + ch * 4 + q;
  }
  j.d[seg][off] = (h16)j.s[seg][soff];
}

// out: nh = h rows 0..63, eh = h rows 128..2111 (both f32).
__global__ void out_kernel(const float* __restrict__ h, float* __restrict__ out) {
  long i = (long)blockIdx.x * 256 + threadIdx.x;  // 1048576
  out[i] = (i < 32768) ? h[i] : h[i + 32768];
}

__global__ void diag_kernel(float* out, int n, float v) {
  int i = blockIdx.x * 256 + threadIdx.x;
  if (i < n) out[i] = (i == 0) ? v : 0.f;
}

// ---------------------------------------------------------------------------
extern "C" void kernel_launch(void* const* d_in, const int* in_sizes, int n_in,
                              void* d_out, int out_size, void* d_ws,
                              size_t ws_size, hipStream_t stream) {
  const float* node_lat = (const float*)d_in[0];
  const float* edge_lat = (const float*)d_in[1];
  const int* eidx = (const int*)d_in[2];
  const float* ncw1 = (const float*)d_in[3];
  const float* ncb1 = (const float*)d_in[4];
  const float* ncw2 = (const float*)d_in[5];
  const float* ncb2 = (const float*)d_in[6];
  const float* ecw1 = (const float*)d_in[7];
  const float* ecb1 = (const float*)d_in[8];
  const float* ecw2 = (const float*)d_in[9];
  const float* ecb2 = (const float*)d_in[10];
  const float* nwih = (const float*)d_in[11];
  const float* nwhh = (const float*)d_in[12];
  const float* nbih = (const float*)d_in[13];
  const float* nbhh = (const float*)d_in[14];
  const float* ewih = (const float*)d_in[15];
  const float* ewhh = (const float*)d_in[16];
  const float* ebih = (const float*)d_in[17];
  const float* ebhh = (const float*)d_in[18];
  const float* wnp = (const float*)d_in[19];
  const float* wps = (const float*)d_in[20];
  const float* wpo = (const float*)d_in[21];

  const int istride = (in_sizes[2] == 2 * 992 * 3 * 2) ? 2 : 1;

  char* wsb = (char*)d_ws;
  size_t cur = 0;
  auto alloc = [&](size_t b) -> char* {
    char* p = wsb + cur;
    cur += (b + 255) & ~(size_t)255;
    return p;
  };

  // ---- fixed region (~43.4 MB); concat layout: node rows 0..127, edge 128..2175
  h16* W1rn = (h16*)alloc(1024 * 512 * 2);
  h16* W1re = (h16*)alloc(1024 * 512 * 2);
  h16* W2rn = (h16*)alloc((size_t)512 * 4096 * 2);
  h16* W2re = (h16*)alloc((size_t)512 * 4096 * 2);
  h16* Wihn = (h16*)alloc(1536 * 512 * 2);
  h16* Whhn = (h16*)alloc(1536 * 512 * 2);
  h16* Wihe = (h16*)alloc(1536 * 512 * 2);
  h16* Whhe = (h16*)alloc(1536 * 512 * 2);
  h16* featc = (h16*)alloc((size_t)2176 * 512 * 2);
  float* h = (float*)alloc((size_t)2176 * 512 * 4);
  h16* hc = (h16*)alloc((size_t)2176 * 512 * 2);
  h16* gi = (h16*)alloc((size_t)2176 * 1536 * 2);
  h16* gh = (h16*)alloc((size_t)2176 * 1536 * 2);
  h16* msgc = (h16*)alloc((size_t)2176 * 512 * 2);
  h16* nm_e = (h16*)alloc((size_t)2048 * 512 * 2);
  int* elist = (int*)alloc(64 * 62 * 4);
  size_t fixedEnd = cur;

  // ---- chunk planning: {imgs, nEdge, e0}; nEdge*36 % 128 == 0 when mixed ----
  struct Chunk { int imgs, nEdge, e0; };
  Chunk plan[9];
  int nch = 0;
  long m1max = 0, m2max = 0;
  for (int t = 0; t < 4 && !nch; ++t) {
    Chunk p[9];
    int n = 0;
    if (t == 0) {
      p[n++] = {2048, 1984, 0};
    } else if (t == 1) {
      p[n++] = {1056, 992, 0};
      p[n++] = {992, 992, 992};
    } else if (t == 2) {
      p[n++] = {64, 0, 0};
      for (int i = 0; i < 4; ++i) p[n++] = {496, 496, 496 * i};
    } else {
      p[n++] = {64, 0, 0};
      for (int i = 0; i < 8; ++i) p[n++] = {248, 248, 248 * i};
    }
    long m1m = 0, m2m = 0;
    for (int i = 0; i < n; ++i) {
      long m1 = ceil128((long)p[i].imgs * 36);
      long m2 = ceil128((long)p[i].imgs * 4);
      if (m1 > m1m) m1m = m1;
      if (m2 > m2m) m2m = m2;
    }
    size_t scr1 = (size_t)m1m * 1024;            // P1 bytes
    size_t c2b = (size_t)m2m * 512 * 4 * 4;      // C2, z=4 (aliases P1)
    if (c2b > scr1) scr1 = c2b;
    size_t need = fixedEnd + ((scr1 + 255) & ~(size_t)255) +
                  (((size_t)m1m * 2048 + 255) & ~(size_t)255) +
                  (((size_t)m2m * 8192 + 255) & ~(size_t)255);
    if (need <= ws_size) {
      nch = n;
      for (int i = 0; i < n; ++i) plan[i] = p[i];
      m1max = m1m;
      m2max = m2m;
    }
  }
  if (!nch) {
    diag_kernel<<<(out_size + 255) / 256, 256, 0, stream>>>(
        (float*)d_out, out_size, (float)((double)ws_size * 1e-6));
    return;
  }
  size_t scr1 = (size_t)m1max * 1024;
  if ((size_t)m2max * 8192 > scr1) scr1 = (size_t)m2max * 8192;
  char* scr = alloc(scr1);
  h16* P1 = (h16*)scr;
  float* C2 = (float*)scr;  // aliases P1 (P1 dead before conv2 writes)
  h16* C1 = (h16*)alloc((size_t)m1max * 2048);
  h16* P2 = (h16*)alloc((size_t)m2max * 8192);

  // ---- weight conversion ----
  Cvt8 cj;
  const float* srcs[8] = {ncw1, ecw1, ncw2, ecw2, nwih, nwhh, ewih, ewhh};
  h16* dsts[8] = {W1rn, W1re, W2rn, W2re, Wihn, Whhn, Wihe, Whhe};
  long sizes[8] = {1024 * 512, 1024 * 512, (long)512 * 4096, (long)512 * 4096,
                   1536 * 512, 1536 * 512, 1536 * 512, 1536 * 512};
  int perms[8] = {0, 0, 1, 1, 0, 0, 0, 0};
  long c = 0;
  for (int i = 0; i < 8; ++i) {
    cj.s[i] = srcs[i];
    cj.d[i] = dsts[i];
    cj.cum[i] = c;
    cj.perm[i] = perms[i];
    c += sizes[i];
  }
  cj.cum[8] = c;
  cvt8_kernel<<<(unsigned)((c + 255) / 256), 256, 0, stream>>>(cj);
  incid_kernel<<<16, 256, 0, stream>>>(eidx, elist, istride);

  // ---- CNN encoders (node appended to chunk 0; per-block weight switch) ----
  for (int ci = 0; ci < nch; ++ci) {
    const Chunk& K = plan[ci];
    long m1 = ceil128((long)K.imgs * 36);
    long m2 = ceil128((long)K.imgs * 4);
    int sw1, sw2;
    if (K.nEdge == 0) { sw1 = 0; sw2 = 0; }                       // all node
    else if (K.nEdge == K.imgs) { sw1 = 1 << 20; sw2 = 1 << 20; } // all edge
    else { sw1 = (K.nEdge * 36) >> 7; sw2 = (K.nEdge * 4) >> 7; }

    im2col1_kernel<<<(unsigned)K.imgs, 256, 0, stream>>>(
        edge_lat + (long)K.e0 * 128 * 49, node_lat, K.nEdge, P1);

    GemmP g1 = {};
    g1.A[0] = P1;
    g1.Bt[0][0] = W1re; g1.Bt[0][1] = W1rn;
    g1.C[0] = C1;
    g1.bias[0][0] = ecb1; g1.bias[0][1] = ncb1;
    g1.M = (int)m1; g1.N = 1024; g1.K = 512; g1.nkt = 16; g1.bmSwitch = sw1;
    gemm_bt<1, 1><<<(unsigned)((m1 >> 7) * 8), 256, 0, stream>>>(g1);

    pool1_kernel<<<(unsigned)(K.imgs * 8), 256, 0, stream>>>(C1, P2);

    GemmP g2 = {};
    g2.A[0] = P2;
    g2.Bt[0][0] = W2re; g2.Bt[0][1] = W2rn;
    g2.C[0] = C2;
    g2.bias[0][0] = nullptr; g2.bias[0][1] = nullptr;
    g2.M = (int)m2; g2.N = 512; g2.K = 4096; g2.nkt = 32; g2.bmSwitch = sw2;
    gemm_bt<0, 1><<<dim3((unsigned)((m2 >> 7) * 4), 1, 4), 256, 0, stream>>>(g2);

    pool2_kernel<<<(unsigned)(K.imgs * 2), 256, 0, stream>>>(
        C2, m2 * 512L, ecb2, ncb2, K.nEdge, K.e0, featc);
  }

  // ---- initial GRU (h = 0): gi = featc @ Wih^T + b_ih ----
  {
    GemmP g = {};
    g.A[0] = featc;
    g.Bt[0][0] = Wihn; g.Bt[0][1] = Wihe;
    g.C[0] = gi;
    g.bias[0][0] = nbih; g.bias[0][1] = ebih;
    g.M = 2176; g.N = 1536; g.K = 512; g.nkt = 16; g.bmSwitch = 1;
    gemm_bt<2, 1><<<(unsigned)(17 * 12), 256, 0, stream>>>(g);
  }
  gru_init_kernel<<<4352, 256, 0, stream>>>(gi, nbhh, ebhh, h, hc);

  // ---- 2 message-passing iterations (ref's 3rd iteration output is dead) ----
  for (int it = 0; it < 2; ++it) {
    message_kernel<<<496, 256, 0, stream>>>(h, eidx, wnp, wps, wpo, msgc, nm_e,
                                            istride);
    gather_kernel<<<64, 256, 0, stream>>>(nm_e, elist, msgc);
    GemmP g = {};
    g.A[0] = msgc; g.A[1] = hc;
    g.Bt[0][0] = Wihn; g.Bt[0][1] = Wihe;
    g.Bt[1][0] = Whhn; g.Bt[1][1] = Whhe;
    g.C[0] = gi; g.C[1] = gh;
    g.bias[0][0] = nbih; g.bias[0][1] = ebih;
    g.bias[1][0] = nbhh; g.bias[1][1] = ebhh;
    g.M = 2176; g.N = 1536; g.K = 512; g.nkt = 16; g.bmSwitch = 1;
    gemm_bt<2, 2><<<dim3(17 * 12, 2), 256, 0, stream>>>(g);
    gru_step_kernel<<<4352, 256, 0, stream>>>(gi, gh, h, hc);
  }

  // ---- output ----
  out_kernel<<<4096, 256, 0, stream>>>(h, (float*)d_out);
}